// Round 3
// baseline (198.950 us; speedup 1.0000x reference)
//
#include <hip/hip_runtime.h>

typedef __bf16 bf16x8 __attribute__((ext_vector_type(8)));
typedef float  f32x4  __attribute__((ext_vector_type(4)));

#define B_      64
#define C_      128
#define M_      4096
#define KCHUNK  8
#define KC      (M_ / KCHUNK)   // 512
#define BK      64
#define NSLAB   (KC / BK)       // 8
#define LSTR    72              // bf16 elems; 144B row stride keeps ds_*_b128 16B-aligned

__device__ __forceinline__ unsigned short f2bf(float f) {
  unsigned u = __builtin_bit_cast(unsigned, f);
  u += 0x7fffu + ((u >> 16) & 1u);          // RNE fp32->bf16
  return (unsigned short)(u >> 16);
}
// unpack a dword holding 2 bf16: elem0 = low16, elem1 = high16
__device__ __forceinline__ float bf_lo(unsigned u) { return __builtin_bit_cast(float, u << 16); }
__device__ __forceinline__ float bf_hi(unsigned u) { return __builtin_bit_cast(float, u & 0xffff0000u); }

// 512 threads = 8 waves. Wave w covers output rows (w>>2)*64 .. +63, cols (w&3)*32 .. +31.
// Staging: thread t covers rows (t>>3) and (t>>3)+64, floats [(t&7)*8, +8) of the 64-wide slab.
__global__ __launch_bounds__(512, 4) void covpool_main(
    const float* __restrict__ x, unsigned short* __restrict__ Gp, float* __restrict__ Sp) {
  __shared__ unsigned short As[2][C_ * LSTR];   // 36 KiB total -> 2 blocks/CU fits

  const int tid  = threadIdx.x;
  const int b    = blockIdx.x >> 3;
  const int ch   = blockIdx.x & 7;

  const int row  = tid >> 3;          // 0..63
  const int col8 = tid & 7;           // 8 floats each

  const float* xp0 = x + ((size_t)(b * C_ + row) * M_) + (size_t)ch * KC + col8 * 8;
  const float* xp1 = xp0 + (size_t)64 * M_;

  const int lane = tid & 63;
  const int wave = tid >> 6;
  const int row0 = (wave >> 2) << 6;  // 0 or 64
  const int col0 = (wave & 3) << 5;   // 0,32,64,96
  const int lrow = lane & 15;
  const int quad = lane >> 4;

  f32x4 acc[4][2];
#pragma unroll
  for (int i = 0; i < 4; ++i)
#pragma unroll
    for (int j = 0; j < 2; ++j)
      acc[i][j] = (f32x4){0.f, 0.f, 0.f, 0.f};

  float sum0 = 0.f, sum1 = 0.f;

  // explicit double-buffer prefetch registers (NO dynamic indexing -> no scratch)
  float4 a0, a1, a2, a3, b0, b1, b2, b3;

  a0 = ((const float4*)xp0)[0]; a1 = ((const float4*)xp0)[1];
  a2 = ((const float4*)xp1)[0]; a3 = ((const float4*)xp1)[1];

  // STAGE: plain (__bf16) casts — the compiler fuses pairs into
  // v_cvt_pk_bf16_f32 on gfx950 (RNE), replacing ~4.5 VALU/elem of
  // manual-RNE bit math with ~0.5/elem. No inline asm (m240: asm form slower).
#define STAGE(BUF, R0, R1, R2, R3)                                                 \
  {                                                                                \
    sum0 += (R0.x + R0.y) + (R0.z + R0.w) + (R1.x + R1.y) + (R1.z + R1.w);         \
    sum1 += (R2.x + R2.y) + (R2.z + R2.w) + (R3.x + R3.y) + (R3.z + R3.w);         \
    bf16x8 v0 = { (__bf16)R0.x, (__bf16)R0.y, (__bf16)R0.z, (__bf16)R0.w,          \
                  (__bf16)R1.x, (__bf16)R1.y, (__bf16)R1.z, (__bf16)R1.w };        \
    bf16x8 v1 = { (__bf16)R2.x, (__bf16)R2.y, (__bf16)R2.z, (__bf16)R2.w,          \
                  (__bf16)R3.x, (__bf16)R3.y, (__bf16)R3.z, (__bf16)R3.w };        \
    *(__shared__ bf16x8*)&As[BUF][row * LSTR + col8 * 8]        = v0;              \
    *(__shared__ bf16x8*)&As[BUF][(64 + row) * LSTR + col8 * 8] = v1;              \
  }

#define COMPUTE(BUF)                                                                \
  {                                                                                 \
    _Pragma("unroll")                                                               \
    for (int ks = 0; ks < 2; ++ks) {                                                \
      const int koff = ks * 32 + quad * 8;                                          \
      bf16x8 af[4], bfr[2];                                                         \
      _Pragma("unroll")                                                             \
      for (int i = 0; i < 4; ++i)                                                   \
        af[i] = *(const __shared__ bf16x8*)&As[BUF][(row0 + i * 16 + lrow) * LSTR + koff]; \
      _Pragma("unroll")                                                             \
      for (int j = 0; j < 2; ++j)                                                   \
        bfr[j] = *(const __shared__ bf16x8*)&As[BUF][(col0 + j * 16 + lrow) * LSTR + koff]; \
      _Pragma("unroll")                                                             \
      for (int i = 0; i < 4; ++i)                                                   \
        _Pragma("unroll")                                                           \
        for (int j = 0; j < 2; ++j)                                                 \
          acc[i][j] = __builtin_amdgcn_mfma_f32_16x16x32_bf16(af[i], bfr[j], acc[i][j], 0, 0, 0); \
    }                                                                               \
  }

  // Prefetch loads are issued AFTER each barrier: the compiler's mandatory
  // `s_waitcnt vmcnt(0)` before `s_barrier` then never drains freshly-issued
  // loads; their ~900cy HBM latency is absorbed by the COMPUTE phase and paid
  // (residually, per-wave) at the register use in the next STAGE.
#pragma unroll
  for (int s = 0; s < NSLAB; s += 2) {
    STAGE(0, a0, a1, a2, a3);
    __syncthreads();
    {  // prefetch slab s+1 (in flight across COMPUTE(0))
      const float* p0 = xp0 + (size_t)(s + 1) * BK;
      const float* p1 = xp1 + (size_t)(s + 1) * BK;
      b0 = ((const float4*)p0)[0]; b1 = ((const float4*)p0)[1];
      b2 = ((const float4*)p1)[0]; b3 = ((const float4*)p1)[1];
    }
    COMPUTE(0);
    STAGE(1, b0, b1, b2, b3);
    __syncthreads();
    if (s + 2 < NSLAB) {  // prefetch slab s+2 (in flight across COMPUTE(1))
      const float* p0 = xp0 + (size_t)(s + 2) * BK;
      const float* p1 = xp1 + (size_t)(s + 2) * BK;
      a0 = ((const float4*)p0)[0]; a1 = ((const float4*)p0)[1];
      a2 = ((const float4*)p1)[0]; a3 = ((const float4*)p1)[1];
    }
    COMPUTE(1);
  }

  // partial G (bf16), layout [ch][b][128][128]
  unsigned short* gout = Gp + (((size_t)ch * B_ + b) << 14);
#pragma unroll
  for (int i = 0; i < 4; ++i)
#pragma unroll
    for (int j = 0; j < 2; ++j)
#pragma unroll
      for (int rr = 0; rr < 4; ++rr)
        gout[(size_t)(row0 + i * 16 + quad * 4 + rr) * C_ + (col0 + j * 16 + lrow)] =
            f2bf(acc[i][j][rr]);

  // row sums: 8 lanes share a row (tid>>3), all within one wave
  sum0 += __shfl_xor(sum0, 1); sum0 += __shfl_xor(sum0, 2); sum0 += __shfl_xor(sum0, 4);
  sum1 += __shfl_xor(sum1, 1); sum1 += __shfl_xor(sum1, 2); sum1 += __shfl_xor(sum1, 4);
  if ((tid & 7) == 0) {
    float* sout = Sp + (((size_t)ch * B_ + b) << 7);
    sout[row]      = sum0;
    sout[64 + row] = sum1;
  }
}

__global__ __launch_bounds__(256) void covpool_fix(
    const unsigned short* __restrict__ Gp, const float* __restrict__ Sp,
    float* __restrict__ y) {
  const int idx = (blockIdx.x * 256 + threadIdx.x) * 8;   // 8 outputs/thread
  const int bb  = idx >> 14;
  const int rem = idx & 16383;
  const int cc  = rem >> 7;
  const int dd  = rem & 127;    // multiple of 8
  float g0 = 0.f, g1 = 0.f, g2 = 0.f, g3 = 0.f;
  float g4 = 0.f, g5 = 0.f, g6 = 0.f, g7 = 0.f;
  float sc = 0.f;
  float4 sd0 = {0.f, 0.f, 0.f, 0.f}, sd1 = {0.f, 0.f, 0.f, 0.f};
#pragma unroll
  for (int ch = 0; ch < KCHUNK; ++ch) {
    uint4 gv = *(const uint4*)&Gp[(((size_t)ch * B_ + bb) << 14) + rem];
    g0 += bf_lo(gv.x); g1 += bf_hi(gv.x);
    g2 += bf_lo(gv.y); g3 += bf_hi(gv.y);
    g4 += bf_lo(gv.z); g5 += bf_hi(gv.z);
    g6 += bf_lo(gv.w); g7 += bf_hi(gv.w);
    const float* sp = Sp + (((size_t)ch * B_ + bb) << 7);
    sc += sp[cc];
    float4 s0 = *(const float4*)&sp[dd];
    float4 s1 = *(const float4*)&sp[dd + 4];
    sd0.x += s0.x; sd0.y += s0.y; sd0.z += s0.z; sd0.w += s0.w;
    sd1.x += s1.x; sd1.y += s1.y; sd1.z += s1.z; sd1.w += s1.w;
  }
  const float invM = 1.f / (float)M_;
  const float scm = sc * invM;
  float4 o0 = { g0 * invM - scm * (sd0.x * invM), g1 * invM - scm * (sd0.y * invM),
                g2 * invM - scm * (sd0.z * invM), g3 * invM - scm * (sd0.w * invM) };
  float4 o1 = { g4 * invM - scm * (sd1.x * invM), g5 * invM - scm * (sd1.y * invM),
                g6 * invM - scm * (sd1.z * invM), g7 * invM - scm * (sd1.w * invM) };
  *(float4*)&y[idx]     = o0;
  *(float4*)&y[idx + 4] = o1;
}

extern "C" void kernel_launch(void* const* d_in, const int* in_sizes, int n_in,
                              void* d_out, int out_size, void* d_ws, size_t ws_size,
                              hipStream_t stream) {
  const float* x = (const float*)d_in[0];
  float* out = (float*)d_out;
  unsigned short* wsG = (unsigned short*)d_ws;              // 8*64*16384 bf16 = 16.8 MB
  float* wsS = (float*)(wsG + (size_t)KCHUNK * B_ * C_ * C_); // 8*64*128 fp32 = 256 KB
  covpool_main<<<dim3(B_ * KCHUNK), dim3(512), 0, stream>>>(x, wsG, wsS);
  covpool_fix<<<dim3((B_ * C_ * C_) / 2048), dim3(256), 0, stream>>>(wsG, wsS, out);
}